// Round 19
// baseline (472.273 us; speedup 1.0000x reference)
//
#include <hip/hip_runtime.h>
#include <hip/hip_bf16.h>
#include <stdint.h>

// ---------------------------------------------------------------------------
// MixModel (MI355X / gfx950), round 19: r18 + nontemporal msg-stream loads.
//
// r18: occupancy 36->56% with dur flat => layer_step memory-bound (3.85TB/s,
// WRITE 166MB compulsory). r17: msg L3 hit rate insensitive to working set.
// Lever: msg-in is single-use; its L3 allocations evict the msg-out lines the
// NEXT layer would hit. NT loads (nt flag) on msg reads keep L3 for written
// lines -> higher next-layer hit rate -> lower FETCH. Stat/panel stay cached.
// Everything else byte-identical to r18 (proven, absmax 0.0078).
// ---------------------------------------------------------------------------

typedef __attribute__((ext_vector_type(4))) float    f32x4;
typedef __attribute__((ext_vector_type(4))) _Float16 f16x4;
typedef __attribute__((ext_vector_type(8))) _Float16 f16x8;
typedef unsigned long long u64;
typedef unsigned int u32;

#define STEP_BYTES 55296            // 9 jt * 6 slices * 64 lanes * 16B
#define PNL_JT     8
#define PNL_SZ     (PNL_JT*6144)    // 49152 -> 3 blocks/CU
#define PHA_SZ     30720            // fused path: jt 0..4
#define PHB_SZ     24576            // fused path: jt 5..8
#define CMN_STRIDE 41472            // fused path: per-mt panel
#define CSL_SZ     46080            // unfused: per-i slice (10 mt * 4608)
#define CPA_SZ     23040
#define CPB_SZ     18432
#define WS_LAYER   (54*STEP_BYTES)  // 2,985,984
#define LDS_TOTAL  (2*PHA_SZ)       // fused path dynamic LDS

__device__ __forceinline__ unsigned short f2h(float f) {
  return __builtin_bit_cast(unsigned short, (_Float16)f);
}
__device__ __forceinline__ u64 as_u64(f16x4 v) { return __builtin_bit_cast(u64, v); }
__device__ __forceinline__ f16x4 as_f16x4(u64 v) { return __builtin_bit_cast(f16x4, v); }

__device__ __forceinline__ f32x4 mfma16(f16x4 a, f16x4 b, f32x4 c) {
#if __has_builtin(__builtin_amdgcn_mfma_f32_16x16x16f16)
  return __builtin_amdgcn_mfma_f32_16x16x16f16(a, b, c, 0, 0, 0);
#else
  asm("v_mfma_f32_16x16x16_f16 %0, %1, %2, %0" : "+v"(c) : "v"(a), "v"(b));
  return c;
#endif
}

__device__ __forceinline__ float static_feat(const float* __restrict__ mask,
                                             const float* __restrict__ board,
                                             int b, int o, int kidx) {
  if (kidx < 9)  return mask [b*81  + o*9 + kidx];
  if (kidx < 18) return board[b*180 +       o*9 + (kidx - 9)];
  if (kidx < 27) return board[b*180 + 90 +  o*9 + (kidx - 18)];
  if (kidx < 36) return board[b*180 +       81 + (kidx - 27)];
  if (kidx < 45) return board[b*180 + 90 +  81 + (kidx - 36)];
  return 0.f;
}

// async stage nbytes (16B-granular, n16 % 64 == 0) into LDS across NTH threads
template<int NTH>
__device__ __forceinline__ void stage_n(const unsigned char* __restrict__ src,
                                        unsigned char* dstlds, int nbytes, int tid) {
  const int n16 = nbytes / 16;
  const int ubase = tid & ~63;
  for (int k = 0; k * NTH < n16; ++k) {
    const int idx = k * NTH + tid;
    if (idx < n16) {
      __builtin_amdgcn_global_load_lds(
          (const __attribute__((address_space(1))) void*)(src + (size_t)idx * 16),
          (__attribute__((address_space(3))) void*)(dstlds + (size_t)(k * NTH + ubase) * 16),
          16, 0, 0);
    }
  }
}

// ===========================================================================
// UNFUSED PATH v5 (v4 + NT msg loads)
// ===========================================================================

// B-chunk loads for one 16-sample tile (coalesced: 512B/chunk/wave)
// msg reads are single-use per layer -> nontemporal (don't displace L3 lines)
template<int P, int FIRST>
__device__ __forceinline__ void load_B(u64 (&B)[12],
    const unsigned char* __restrict__ stat, const unsigned char* __restrict__ msg,
    int o, int b0, int s15, int hq, int Bt)
{
  const size_t lo = (size_t)(b0 + s15) * 32 + (size_t)hq * 8;
  B[0] = *(const u64*)(stat + ((size_t)(o * 2 + 0) * Bt) * 32 + lo);
  B[1] = *(const u64*)(stat + ((size_t)(o * 2 + 1) * Bt) * 32 + lo);
  B[2] = *(const u64*)(stat + ((size_t)18 * Bt) * 32 + lo);
  if (!FIRST) {
#pragma unroll
    for (int i = 0; i < 9; ++i) {
      const int cell = P ? (o * 9 + i) : (i * 9 + o);
      B[3 + i] = __builtin_nontemporal_load(
          (const u64*)(msg + ((size_t)cell * Bt) * 32 + lo));
    }
  }
}

// one layer: grid (Bt/256, 9), 512 thr = 8 waves; wave owns 32 samples
// (2 tiles, B in regs). jt 0..7 A-panel in LDS; jt 8 read from global (L2).
template<int P, int FIRST>
__global__ __launch_bounds__(512, 6) void layer_step(
    const unsigned char* __restrict__ wsLW, const unsigned char* __restrict__ stat,
    unsigned char* __restrict__ msg, int d, int Bt)
{
  __shared__ unsigned char panel[PNL_SZ];
  const int tid = threadIdx.x;
  const int lane = tid & 63;
  const int wid = tid >> 6;
  const int o = blockIdx.y;
  const int s15 = lane & 15, hq = lane >> 4;
  const unsigned char* gpanel = wsLW + (size_t)(d * 9 + o) * STEP_BYTES;

  stage_n<512>(gpanel, panel, PNL_SZ, tid);

  const int b0 = blockIdx.x * 256 + wid * 32;
  u64 B0[12], B1[12];
  load_B<P, FIRST>(B0, stat, msg, o, b0,      s15, hq, Bt);
  load_B<P, FIRST>(B1, stat, msg, o, b0 + 16, s15, hq, Bt);

  asm volatile("s_waitcnt vmcnt(0)" ::: "memory");
  __syncthreads();   // panel + B ready

  const unsigned char* pl = panel + (size_t)lane * 16;
  const unsigned char* gl = gpanel + (size_t)lane * 16;
  const size_t lo0 = (size_t)(b0 + s15) * 32 + (size_t)hq * 8;
  const size_t lo1 = lo0 + 16 * 32;
#pragma unroll
  for (int jj = 0; jj < 9; ++jj) {
    const int j = (jj == 0) ? 8 : (jj - 1);   // j=8 (global A) first
    f32x4 a0 = 0.f, a1 = 0.f;
#pragma unroll
    for (int s = 0; s < (FIRST ? 2 : 6); ++s) {
      f16x8 af;
      if (j >= PNL_JT) af = *(const f16x8*)(gl + j * 6144 + s * 1024);
      else             af = *(const f16x8*)(pl + j * 6144 + s * 1024);
      const f16x4 alo = __builtin_shufflevector(af, af, 0, 1, 2, 3);
      a0 = mfma16(alo, as_f16x4(B0[2 * s]), a0);
      a1 = mfma16(alo, as_f16x4(B1[2 * s]), a1);
      if (!FIRST || s == 0) {
        const f16x4 ahi = __builtin_shufflevector(af, af, 4, 5, 6, 7);
        a0 = mfma16(ahi, as_f16x4(B0[2 * s + 1]), a0);
        a1 = mfma16(ahi, as_f16x4(B1[2 * s + 1]), a1);
      }
    }
    f16x4 h0, h1;
#pragma unroll
    for (int r = 0; r < 4; ++r) {
      h0[r] = (_Float16)fmaxf(a0[r], 0.f);
      h1[r] = (_Float16)fmaxf(a1[r], 0.f);
    }
    const int wcell = P ? (o * 9 + j) : (j * 9 + o);
    unsigned char* wp = msg + ((size_t)wcell * Bt) * 32;
    *(u64*)(wp + lo0) = as_u64(h0);
    *(u64*)(wp + lo1) = as_u64(h1);
  }
}

// common layer: grid (Bt/128), 256 thr = 4 waves; wave owns 32 samples;
// acc[2][10] in regs; wdl head fused via shfl reduce (r16-proven).
__global__ __launch_bounds__(256, 3) void common_unf(
    const unsigned char* __restrict__ wsCW, const unsigned char* __restrict__ msg,
    const float* __restrict__ common_b, const float* __restrict__ wdl_w,
    const float* __restrict__ wdl_b, float* __restrict__ out, int Bt)
{
  __shared__ unsigned char sl[CSL_SZ];
  const int tid = threadIdx.x;
  const int lane = tid & 63;
  const int wid = tid >> 6;
  const int s15 = lane & 15, hq = lane >> 4;
  const int b0 = blockIdx.x * 128 + wid * 32;
  const size_t lo0 = (size_t)(b0 + s15) * 32 + (size_t)hq * 8;
  const size_t lo1 = lo0 + 16 * 32;

  f32x4 acc0[10], acc1[10];
#pragma unroll
  for (int mt = 0; mt < 10; ++mt) { acc0[mt] = 0.f; acc1[mt] = 0.f; }

  for (int i = 0; i < 9; ++i) {
    __syncthreads();            // all waves done reading previous slice
    stage_n<256>(wsCW + (size_t)i * CSL_SZ, sl, CSL_SZ, tid);

    u64 m0[9], m1[9];
#pragma unroll
    for (int jj = 0; jj < 9; ++jj) {
      const unsigned char* mp = msg + ((size_t)(i * 9 + jj) * Bt) * 32;
      m0[jj] = __builtin_nontemporal_load((const u64*)(mp + lo0));
      m1[jj] = __builtin_nontemporal_load((const u64*)(mp + lo1));
    }
    asm volatile("s_waitcnt vmcnt(0)" ::: "memory");
    __syncthreads();

#pragma unroll
    for (int mt = 0; mt < 10; ++mt) {
      const unsigned char* base = sl + mt * 4608;
#pragma unroll
      for (int p = 0; p < 4; ++p) {
        const f16x8 a8 = *(const f16x8*)(base + p * 1024 + (size_t)lane * 16);
        const f16x4 alo = __builtin_shufflevector(a8, a8, 0, 1, 2, 3);
        const f16x4 ahi = __builtin_shufflevector(a8, a8, 4, 5, 6, 7);
        acc0[mt] = mfma16(alo, as_f16x4(m0[2 * p]),     acc0[mt]);
        acc1[mt] = mfma16(alo, as_f16x4(m1[2 * p]),     acc1[mt]);
        acc0[mt] = mfma16(ahi, as_f16x4(m0[2 * p + 1]), acc0[mt]);
        acc1[mt] = mfma16(ahi, as_f16x4(m1[2 * p + 1]), acc1[mt]);
      }
      const f16x4 al = *(const f16x4*)(base + 4096 + (size_t)lane * 8);
      acc0[mt] = mfma16(al, as_f16x4(m0[8]), acc0[mt]);
      acc1[mt] = mfma16(al, as_f16x4(m1[8]), acc1[mt]);
    }
  }

  float pw0[3] = {0.f, 0.f, 0.f}, pw1[3] = {0.f, 0.f, 0.f};
#pragma unroll
  for (int mt = 0; mt < 10; ++mt) {
#pragma unroll
    for (int r = 0; r < 4; ++r) {
      const int c = mt * 16 + 4 * hq + r;
      if (c < 81) {   // policy (no relu)
        out[(size_t)3 * Bt + (size_t)(b0 + s15) * 81 + c]      = acc0[mt][r] + common_b[c];
        out[(size_t)3 * Bt + (size_t)(b0 + 16 + s15) * 81 + c] = acc1[mt][r] + common_b[c];
      } else if (c < 145) {
        const float h0 = fmaxf(acc0[mt][r] + common_b[c], 0.f);
        const float h1 = fmaxf(acc1[mt][r] + common_b[c], 0.f);
        const int cc = c - 81;
#pragma unroll
        for (int w = 0; w < 3; ++w) {
          const float wv = wdl_w[cc * 3 + w];
          pw0[w] += h0 * wv;
          pw1[w] += h1 * wv;
        }
      }
    }
  }
#pragma unroll
  for (int w = 0; w < 3; ++w) {
    float v0 = pw0[w], v1 = pw1[w];
    v0 += __shfl_xor(v0, 16, 64); v0 += __shfl_xor(v0, 32, 64);
    v1 += __shfl_xor(v1, 16, 64); v1 += __shfl_xor(v1, 32, 64);
    if (hq == 0) {
      const float bb = wdl_b[w];
      out[(size_t)(b0 + s15) * 3 + w]      = v0 + bb;
      out[(size_t)(b0 + 16 + s15) * 3 + w] = v1 + bb;
    }
  }
}

// prologue: pack static features -> B-chunk layout (coalesced via LDS)
__global__ __launch_bounds__(256) void conv_static(
    const float* __restrict__ mask, const float* __restrict__ board,
    unsigned char* __restrict__ stat, int Bt)
{
  __shared__ float sm[16 * 81];
  __shared__ float sb[16 * 180];
  const int tid = threadIdx.x;
  const int base_b = blockIdx.x * 16;

  const float4* gm = (const float4*)(mask + (size_t)base_b * 81);
  for (int idx = tid; idx < 324; idx += 256) ((float4*)sm)[idx] = gm[idx];
  const float4* gb = (const float4*)(board + (size_t)base_b * 180);
  for (int idx = tid; idx < 720; idx += 256) ((float4*)sb)[idx] = gb[idx];
  __syncthreads();

  const int lane = tid & 63, wv = tid >> 6;
  const int s15 = lane & 15, hq = lane >> 4;
  const float* lm = sm + s15 * 81;
  const float* lb = sb + s15 * 180;
  for (int slot = wv; slot < 19; slot += 4) {
    const int o = (slot < 18) ? (slot >> 1) : 0;
    const int c = (slot < 18) ? (slot & 1) : 2;
    unsigned short v[4];
#pragma unroll
    for (int e = 0; e < 4; ++e) {
      const int kidx = c * 16 + 4 * hq + e;
      float f;
      if (kidx < 9)        f = lm[o * 9 + kidx];
      else if (kidx < 18)  f = lb[o * 9 + (kidx - 9)];
      else if (kidx < 27)  f = lb[90 + o * 9 + (kidx - 18)];
      else if (kidx < 36)  f = lb[81 + (kidx - 27)];
      else if (kidx < 45)  f = lb[90 + 81 + (kidx - 36)];
      else                 f = (kidx == 45) ? 1.f : 0.f;
      v[e] = f2h(f);
    }
    const u32 w0 = (u32)v[0] | ((u32)v[1] << 16);
    const u32 w1 = (u32)v[2] | ((u32)v[3] << 16);
    *(uint2*)(stat + ((size_t)slot * Bt + base_b + s15) * 32 + (size_t)hq * 8)
        = make_uint2(w0, w1);
  }
}

// prologue: common weights -> i-MAJOR fp16 fragment layout (unfused path)
__global__ __launch_bounds__(256) void conv_common_w2(const float* __restrict__ cw,
                                                      unsigned char* __restrict__ dst) {
  const int gid = blockIdx.x * 256 + threadIdx.x;
  const int NPAIR = 10 * 36 * 64;
  if (gid < NPAIR) {
    const int lane = gid & 63;
    const int t = gid >> 6;
    const int p = t % 4, t2 = t / 4;
    const int i = t2 % 9, mt = t2 / 9;
    const int m = lane & 15, hq = lane >> 4;
    const int c = mt * 16 + m;
    unsigned short v[8];
#pragma unroll
    for (int e = 0; e < 8; ++e) {
      const int ci = i * 9 + 2 * p + (e >> 2);
      const int k = ci * 16 + 4 * hq + (e & 3);
      v[e] = f2h((c < 145) ? cw[(size_t)k * 145 + c] : 0.f);
    }
    const u32 w0 = (u32)v[0] | ((u32)v[1] << 16);
    const u32 w1 = (u32)v[2] | ((u32)v[3] << 16);
    const u32 w2 = (u32)v[4] | ((u32)v[5] << 16);
    const u32 w3 = (u32)v[6] | ((u32)v[7] << 16);
    *(uint4*)(dst + (size_t)i * CSL_SZ + (size_t)mt * 4608
              + (size_t)p * 1024 + (size_t)lane * 16) = make_uint4(w0, w1, w2, w3);
  } else if (gid < NPAIR + 10 * 9 * 64) {
    const int g = gid - NPAIR;
    const int lane = g & 63;
    const int t = g >> 6;
    const int i = t % 9, mt = t / 9;
    const int m = lane & 15, hq = lane >> 4;
    const int c = mt * 16 + m;
    unsigned short v[4];
#pragma unroll
    for (int e = 0; e < 4; ++e) {
      const int k = (i * 9 + 8) * 16 + 4 * hq + e;
      v[e] = f2h((c < 145) ? cw[(size_t)k * 145 + c] : 0.f);
    }
    const u32 w0 = (u32)v[0] | ((u32)v[1] << 16);
    const u32 w1 = (u32)v[2] | ((u32)v[3] << 16);
    *(uint2*)(dst + (size_t)i * CSL_SZ + (size_t)mt * 4608
              + 4096 + (size_t)lane * 8) = make_uint2(w0, w1);
  }
}

// ===========================================================================
// FUSED FALLBACK (r10, proven 734us) + its mt-major common-W prologue
// ===========================================================================

template<int P, int O, int J0, int J1, int OFF>
__device__ __forceinline__ void jt_range(const unsigned char* __restrict__ buf,
    u64 (&msg)[9][9], const u64 (&msgc)[9], f16x4 st0, f16x4 st1, f16x4 stc, int lane)
{
  const unsigned char* abase = buf + (size_t)lane * 16 - OFF;
#pragma unroll
  for (int j = J0; j < J1; ++j) {
    f32x4 acc = 0.f;
#pragma unroll
    for (int sp = 0; sp < 6; ++sp) {
      const f16x8 af = *(const f16x8*)(abase + j * 6144 + sp * 1024);
      const f16x4 alo = __builtin_shufflevector(af, af, 0, 1, 2, 3);
      const f16x4 ahi = __builtin_shufflevector(af, af, 4, 5, 6, 7);
      const int c0 = 2 * sp, c1 = 2 * sp + 1;
      if (c0 == 0)      acc = mfma16(alo, st0, acc);
      else if (c0 == 2) acc = mfma16(alo, stc, acc);
      else              acc = mfma16(alo, as_f16x4(msgc[c0 - 3]), acc);
      if (c1 == 1)      acc = mfma16(ahi, st1, acc);
      else              acc = mfma16(ahi, as_f16x4(msgc[c1 - 3]), acc);
    }
    f16x4 h;
#pragma unroll
    for (int r = 0; r < 4; ++r)
      h[r] = (_Float16)fmaxf(acc[r], 0.f);
    if (P) msg[O][j] = as_u64(h); else msg[j][O] = as_u64(h);
  }
}

template<int P, int O>
__device__ __forceinline__ void do_step_layer(int base, const unsigned char* __restrict__ ws,
    unsigned char* bufA, unsigned char* bufB, u64 (&msg)[9][9],
    u64 sb, u32 sb8, f16x4 stc, int lane, int tid)
{
  const int step = base + P * 9 + O;
  asm volatile("s_waitcnt vmcnt(0)" ::: "memory");
  __syncthreads();
  stage_n<256>(ws + (size_t)step * STEP_BYTES + PHA_SZ, bufB, PHB_SZ, tid);
  f16x4 st0, st1;
  {
    const u32 byt = (O < 8) ? ((u32)(sb >> (O * 8)) & 0xFFu) : sb8;
#pragma unroll
    for (int e = 0; e < 4; ++e) {
      st0[e] = (_Float16)(float)((byt >> e) & 1u);
      st1[e] = (_Float16)(float)((byt >> (4 + e)) & 1u);
    }
  }
  u64 msgc[9];
#pragma unroll
  for (int i = 0; i < 9; ++i)
    msgc[i] = P ? msg[O][i] : msg[i][O];
  jt_range<P, O, 0, 5, 0>(bufA, msg, msgc, st0, st1, stc, lane);
  asm volatile("s_waitcnt vmcnt(0)" ::: "memory");
  __syncthreads();
  if (step + 1 < 54)
    stage_n<256>(ws + (size_t)(step + 1) * STEP_BYTES, bufA, PHA_SZ, tid);
  else
    stage_n<256>(ws + WS_LAYER, bufA, CPA_SZ, tid);
  jt_range<P, O, 5, 9, PHA_SZ>(bufB, msg, msgc, st0, st1, stc, lane);
}

__global__ __launch_bounds__(256, 1) void mix_main(
    const float* __restrict__ mask, const float* __restrict__ board,
    const float* __restrict__ common_b, const float* __restrict__ wdl_w,
    const float* __restrict__ wdl_b, const unsigned char* __restrict__ ws,
    float* __restrict__ out, int Bt)
{
  extern __shared__ unsigned char lds[];
  const int tid = threadIdx.x;
  const int lane = tid & 63;
  const int wid = tid >> 6;
  const int s15 = lane & 15, hq = lane >> 4;
  const int b0 = blockIdx.x * 64 + wid * 16;
  unsigned char* bufA = lds;
  unsigned char* bufB = lds + PHA_SZ;

  stage_n<256>(ws, bufA, PHA_SZ, tid);

  u64 msg[9][9];
#pragma unroll
  for (int a = 0; a < 9; ++a)
#pragma unroll
    for (int b = 0; b < 9; ++b) msg[a][b] = 0ull;

  u64 sb = 0ull;
  u32 sb8 = 0u;
  {
    const int b = b0 + s15;
#pragma unroll
    for (int o = 0; o < 9; ++o)
#pragma unroll
      for (int e = 0; e < 4; ++e) {
        const u32 bit0 = static_feat(mask, board, b, o,      4 * hq + e) > 0.5f;
        const u32 bit1 = static_feat(mask, board, b, o, 16 + 4 * hq + e) > 0.5f;
        if (o < 8) sb |= ((u64)bit0 << (o * 8 + e)) | ((u64)bit1 << (o * 8 + 4 + e));
        else       sb8 |= (bit0 << e) | (bit1 << (4 + e));
      }
  }
  f16x4 stc;
  {
    const int b = b0 + s15;
#pragma unroll
    for (int e = 0; e < 4; ++e) {
      const int kidx = 32 + 4 * hq + e;
      stc[e] = (_Float16)((kidx == 45) ? 1.f : static_feat(mask, board, b, 0, kidx));
    }
  }

#define DO_POS(P, O) do_step_layer<P, O>(base, ws, bufA, bufB, msg, sb, sb8, stc, lane, tid);
  for (int dp = 0; dp < 3; ++dp) {
    const int base = dp * 18;
    DO_POS(0,0) DO_POS(0,1) DO_POS(0,2) DO_POS(0,3) DO_POS(0,4)
    DO_POS(0,5) DO_POS(0,6) DO_POS(0,7) DO_POS(0,8)
    DO_POS(1,0) DO_POS(1,1) DO_POS(1,2) DO_POS(1,3) DO_POS(1,4)
    DO_POS(1,5) DO_POS(1,6) DO_POS(1,7) DO_POS(1,8)
  }
#undef DO_POS

  float pw[3] = {0.f, 0.f, 0.f};
  for (int mt = 0; mt < 10; ++mt) {
    asm volatile("s_waitcnt vmcnt(0)" ::: "memory");
    __syncthreads();
    stage_n<256>(ws + WS_LAYER + (size_t)mt * CMN_STRIDE + CPA_SZ, bufB, CPB_SZ, tid);
    f32x4 a0 = 0.f;
#pragma unroll
    for (int i = 0; i < 5; ++i) {
      const unsigned char* base = bufA + i * 4608;
#pragma unroll
      for (int p = 0; p < 4; ++p) {
        const f16x8 af = *(const f16x8*)(base + p * 1024 + (size_t)lane * 16);
        const f16x4 alo = __builtin_shufflevector(af, af, 0, 1, 2, 3);
        const f16x4 ahi = __builtin_shufflevector(af, af, 4, 5, 6, 7);
        a0 = mfma16(alo, as_f16x4(msg[i][2 * p]),     a0);
        a0 = mfma16(ahi, as_f16x4(msg[i][2 * p + 1]), a0);
      }
      const f16x4 al = *(const f16x4*)(bufA + i * 4608 + 4096 + (size_t)lane * 8);
      a0 = mfma16(al, as_f16x4(msg[i][8]), a0);
    }
    asm volatile("s_waitcnt vmcnt(0)" ::: "memory");
    __syncthreads();
    if (mt + 1 < 10)
      stage_n<256>(ws + WS_LAYER + (size_t)(mt + 1) * CMN_STRIDE, bufA, CPA_SZ, tid);
#pragma unroll
    for (int i = 5; i < 9; ++i) {
      const unsigned char* base = bufB + i * 4608 - CPA_SZ;
#pragma unroll
      for (int p = 0; p < 4; ++p) {
        const f16x8 af = *(const f16x8*)(base + p * 1024 + (size_t)lane * 16);
        const f16x4 alo = __builtin_shufflevector(af, af, 0, 1, 2, 3);
        const f16x4 ahi = __builtin_shufflevector(af, af, 4, 5, 6, 7);
        a0 = mfma16(alo, as_f16x4(msg[i][2 * p]),     a0);
        a0 = mfma16(ahi, as_f16x4(msg[i][2 * p + 1]), a0);
      }
      const f16x4 al = *(const f16x4*)(base + 4096 + (size_t)lane * 8);
      a0 = mfma16(al, as_f16x4(msg[i][8]), a0);
    }
#pragma unroll
    for (int r = 0; r < 4; ++r) {
      const int c = mt * 16 + 4 * hq + r;
      const float bias = (c < 145) ? common_b[c] : 0.f;
      const float v0 = a0[r] + bias;
      if (c < 81) {
        out[(size_t)3 * Bt + (size_t)(b0 + s15) * 81 + c] = v0;
      } else if (c < 145) {
        const float h0 = fmaxf(v0, 0.f);
        const int cc = c - 81;
#pragma unroll
        for (int w = 0; w < 3; ++w)
          pw[w] += h0 * wdl_w[cc * 3 + w];
      }
    }
  }
#pragma unroll
  for (int w = 0; w < 3; ++w) {
    float v0 = pw[w];
    v0 += __shfl_xor(v0, 16, 64); v0 += __shfl_xor(v0, 32, 64);
    if (hq == 0)
      out[(size_t)(b0 + s15) * 3 + w] = v0 + wdl_b[w];
  }
}

// ===========================================================================
// SHARED / FUSED PROLOGUES (r10-proven layouts)
// ===========================================================================

__global__ __launch_bounds__(256) void conv_layer_w(const float* __restrict__ lw,
                                                    const float* __restrict__ lb,
                                                    unsigned char* __restrict__ dst) {
  const int gid = blockIdx.x * 256 + threadIdx.x;
  if (gid >= 54 * 9 * 6 * 64) return;
  const int lane = gid & 63;
  const int t = gid >> 6;
  const int kp = t % 6, t2 = t / 6;
  const int jp = t2 % 9, dop = t2 / 9;
  const int m = lane & 15, hq = lane >> 4;
  unsigned short v[8];
#pragma unroll
  for (int e = 0; e < 8; ++e) {
    const int kc = kp * 2 + (e >> 2);
    const int kidx = kc * 16 + 4 * hq + (e & 3);
    float f = 0.f;
    if (kidx < 45)        f = lw[((size_t)dop * 189 + kidx) * 144 + jp * 16 + m];
    else if (kidx == 45)  f = lb[(size_t)dop * 144 + jp * 16 + m];
    else if (kidx >= 48)  f = lw[((size_t)dop * 189 + (kidx - 3)) * 144 + jp * 16 + m];
    v[e] = f2h(f);
  }
  const u32 w0 = (u32)v[0] | ((u32)v[1] << 16);
  const u32 w1 = (u32)v[2] | ((u32)v[3] << 16);
  const u32 w2 = (u32)v[4] | ((u32)v[5] << 16);
  const u32 w3 = (u32)v[6] | ((u32)v[7] << 16);
  *(uint4*)(dst + (size_t)gid * 16) = make_uint4(w0, w1, w2, w3);
}

__global__ __launch_bounds__(256) void conv_common_w(const float* __restrict__ cw,
                                                     unsigned char* __restrict__ dst) {
  const int gid = blockIdx.x * 256 + threadIdx.x;
  const int NPAIR = 10 * 36 * 64;
  if (gid < NPAIR) {
    const int lane = gid & 63;
    const int t = gid >> 6;
    const int p = t % 4, t2 = t / 4;
    const int i = t2 % 9, mt = t2 / 9;
    const int m = lane & 15, hq = lane >> 4;
    const int c = mt * 16 + m;
    unsigned short v[8];
#pragma unroll
    for (int e = 0; e < 8; ++e) {
      const int ci = i * 9 + 2 * p + (e >> 2);
      const int k = ci * 16 + 4 * hq + (e & 3);
      v[e] = f2h((c < 145) ? cw[(size_t)k * 145 + c] : 0.f);
    }
    const u32 w0 = (u32)v[0] | ((u32)v[1] << 16);
    const u32 w1 = (u32)v[2] | ((u32)v[3] << 16);
    const u32 w2 = (u32)v[4] | ((u32)v[5] << 16);
    const u32 w3 = (u32)v[6] | ((u32)v[7] << 16);
    *(uint4*)(dst + (size_t)WS_LAYER + (size_t)mt * CMN_STRIDE + (size_t)i * 4608
              + (size_t)p * 1024 + (size_t)lane * 16) = make_uint4(w0, w1, w2, w3);
  } else if (gid < NPAIR + 10 * 9 * 64) {
    const int g = gid - NPAIR;
    const int lane = g & 63;
    const int t = g >> 6;
    const int i = t % 9, mt = t / 9;
    const int m = lane & 15, hq = lane >> 4;
    const int c = mt * 16 + m;
    unsigned short v[4];
#pragma unroll
    for (int e = 0; e < 4; ++e) {
      const int k = (i * 9 + 8) * 16 + 4 * hq + e;
      v[e] = f2h((c < 145) ? cw[(size_t)k * 145 + c] : 0.f);
    }
    const u32 w0 = (u32)v[0] | ((u32)v[1] << 16);
    const u32 w1 = (u32)v[2] | ((u32)v[3] << 16);
    *(uint2*)(dst + (size_t)WS_LAYER + (size_t)mt * CMN_STRIDE + (size_t)i * 4608
              + 4096 + (size_t)lane * 8) = make_uint2(w0, w1);
  }
}

// ===========================================================================

extern "C" void kernel_launch(void* const* d_in, const int* in_sizes, int n_in,
                              void* d_out, int out_size, void* d_ws, size_t ws_size,
                              hipStream_t stream) {
  const float* mask     = (const float*)d_in[0];
  const float* board    = (const float*)d_in[1];
  const float* layer_w  = (const float*)d_in[2];
  const float* layer_b  = (const float*)d_in[3];
  const float* common_w = (const float*)d_in[4];
  const float* common_b = (const float*)d_in[5];
  const float* wdl_w    = (const float*)d_in[6];
  const float* wdl_b    = (const float*)d_in[7];
  float* out = (float*)d_out;
  unsigned char* ws = (unsigned char*)d_ws;
  const int Bt = in_sizes[0] / 81;   // 65536

  // ws layout (CW region shared by both paths at WS_LAYER, layouts differ)
  const size_t WS_CW_OFF   = (size_t)WS_LAYER;
  const size_t WS_STAT_OFF = WS_CW_OFF + (size_t)9 * CSL_SZ;
  const size_t WS_MSG_OFF  = WS_STAT_OFF + (size_t)19 * Bt * 32;
  const size_t WS_NEED     = WS_MSG_OFF + (size_t)81 * Bt * 32;

  hipLaunchKernelGGL(conv_layer_w, dim3((54 * 9 * 6 * 64) / 256), dim3(256), 0, stream,
                     layer_w, layer_b, ws);

  if (ws_size >= WS_NEED) {
    unsigned char* stat = ws + WS_STAT_OFF;
    unsigned char* msgp = ws + WS_MSG_OFF;

    hipLaunchKernelGGL(conv_common_w2, dim3((10 * (36 + 9) * 64 + 255) / 256), dim3(256),
                       0, stream, common_w, ws + WS_CW_OFF);
    hipLaunchKernelGGL(conv_static, dim3(Bt / 16), dim3(256), 0, stream,
                       mask, board, stat, Bt);

    const dim3 lgrid(Bt / 256, 9);
    hipLaunchKernelGGL((layer_step<0, 1>), lgrid, dim3(512), 0, stream, ws, stat, msgp, 0, Bt);
    hipLaunchKernelGGL((layer_step<1, 0>), lgrid, dim3(512), 0, stream, ws, stat, msgp, 1, Bt);
    hipLaunchKernelGGL((layer_step<0, 0>), lgrid, dim3(512), 0, stream, ws, stat, msgp, 2, Bt);
    hipLaunchKernelGGL((layer_step<1, 0>), lgrid, dim3(512), 0, stream, ws, stat, msgp, 3, Bt);
    hipLaunchKernelGGL((layer_step<0, 0>), lgrid, dim3(512), 0, stream, ws, stat, msgp, 4, Bt);
    hipLaunchKernelGGL((layer_step<1, 0>), lgrid, dim3(512), 0, stream, ws, stat, msgp, 5, Bt);

    hipLaunchKernelGGL(common_unf, dim3(Bt / 128), dim3(256), 0, stream,
                       ws + WS_CW_OFF, msgp, common_b, wdl_w, wdl_b, out, Bt);
  } else {
    hipLaunchKernelGGL(conv_common_w, dim3((10 * (36 + 9) * 64 + 255) / 256), dim3(256),
                       0, stream, common_w, ws);
    (void)hipFuncSetAttribute((const void*)mix_main,
                              hipFuncAttributeMaxDynamicSharedMemorySize, LDS_TOTAL);
    hipLaunchKernelGGL(mix_main, dim3(Bt / 64), dim3(256), LDS_TOTAL, stream,
                       mask, board, common_b, wdl_w, wdl_b, ws, out, Bt);
  }
}

// Round 20
// 447.088 us; speedup vs baseline: 1.0563x; 1.0563x over previous
//
#include <hip/hip_runtime.h>
#include <hip/hip_bf16.h>
#include <stdint.h>

// ---------------------------------------------------------------------------
// MixModel (MI355X / gfx950), round 20: r18 base (NT reverted) + bitmask stat.
//
// r19: NT msg loads null/negative -> reverted. Remaining reducible stream:
// stat (42MB/layer of fp16 fragments encoding BINARY features). Pack as
// bitmasks: 16B per (sample,hq) = 4MB total (L2-resident), rebuilt into
// st0/st1/stc fragments with ~25 VALU once per block (VALUBusy only 20%).
// Bitmask scheme byte-identical to the r5-r13 fused kernel (proven); chunk-2
// bits added to the u32 word. Everything else identical to r18 (absmax .0078).
// ---------------------------------------------------------------------------

typedef __attribute__((ext_vector_type(4))) float    f32x4;
typedef __attribute__((ext_vector_type(4))) _Float16 f16x4;
typedef __attribute__((ext_vector_type(8))) _Float16 f16x8;
typedef unsigned long long u64;
typedef unsigned int u32;

#define STEP_BYTES 55296            // 9 jt * 6 slices * 64 lanes * 16B
#define PNL_JT     8
#define PNL_SZ     (PNL_JT*6144)    // 49152 -> 3 blocks/CU
#define PHA_SZ     30720            // fused path: jt 0..4
#define PHB_SZ     24576            // fused path: jt 5..8
#define CMN_STRIDE 41472            // fused path: per-mt panel
#define CSL_SZ     46080            // unfused: per-i slice (10 mt * 4608)
#define CPA_SZ     23040
#define CPB_SZ     18432
#define WS_LAYER   (54*STEP_BYTES)  // 2,985,984
#define LDS_TOTAL  (2*PHA_SZ)       // fused path dynamic LDS

__device__ __forceinline__ unsigned short f2h(float f) {
  return __builtin_bit_cast(unsigned short, (_Float16)f);
}
__device__ __forceinline__ u64 as_u64(f16x4 v) { return __builtin_bit_cast(u64, v); }
__device__ __forceinline__ f16x4 as_f16x4(u64 v) { return __builtin_bit_cast(f16x4, v); }

__device__ __forceinline__ f32x4 mfma16(f16x4 a, f16x4 b, f32x4 c) {
#if __has_builtin(__builtin_amdgcn_mfma_f32_16x16x16f16)
  return __builtin_amdgcn_mfma_f32_16x16x16f16(a, b, c, 0, 0, 0);
#else
  asm("v_mfma_f32_16x16x16_f16 %0, %1, %2, %0" : "+v"(c) : "v"(a), "v"(b));
  return c;
#endif
}

__device__ __forceinline__ float static_feat(const float* __restrict__ mask,
                                             const float* __restrict__ board,
                                             int b, int o, int kidx) {
  if (kidx < 9)  return mask [b*81  + o*9 + kidx];
  if (kidx < 18) return board[b*180 +       o*9 + (kidx - 9)];
  if (kidx < 27) return board[b*180 + 90 +  o*9 + (kidx - 18)];
  if (kidx < 36) return board[b*180 +       81 + (kidx - 27)];
  if (kidx < 45) return board[b*180 + 90 +  81 + (kidx - 36)];
  return 0.f;
}

// async stage nbytes (16B-granular, n16 % 64 == 0) into LDS across NTH threads
template<int NTH>
__device__ __forceinline__ void stage_n(const unsigned char* __restrict__ src,
                                        unsigned char* dstlds, int nbytes, int tid) {
  const int n16 = nbytes / 16;
  const int ubase = tid & ~63;
  for (int k = 0; k * NTH < n16; ++k) {
    const int idx = k * NTH + tid;
    if (idx < n16) {
      __builtin_amdgcn_global_load_lds(
          (const __attribute__((address_space(1))) void*)(src + (size_t)idx * 16),
          (__attribute__((address_space(3))) void*)(dstlds + (size_t)(k * NTH + ubase) * 16),
          16, 0, 0);
    }
  }
}

// ===========================================================================
// UNFUSED PATH v6 (v4 + bitmask stat)
// ===========================================================================

// one layer: grid (Bt/256, 9), 512 thr = 8 waves; wave owns 32 samples
// (2 tiles, msg B in regs). jt 0..7 A-panel in LDS; jt 8 read from global.
// static fragments rebuilt from 16B/sample-hq packed bitmask (L2-resident).
template<int P, int FIRST>
__global__ __launch_bounds__(512, 6) void layer_step(
    const unsigned char* __restrict__ wsLW, const unsigned char* __restrict__ stat2,
    unsigned char* __restrict__ msg, int d, int Bt)
{
  __shared__ unsigned char panel[PNL_SZ];
  const int tid = threadIdx.x;
  const int lane = tid & 63;
  const int wid = tid >> 6;
  const int o = blockIdx.y;
  const int s15 = lane & 15, hq = lane >> 4;
  const unsigned char* gpanel = wsLW + (size_t)(d * 9 + o) * STEP_BYTES;

  stage_n<512>(gpanel, panel, PNL_SZ, tid);

  const int b0 = blockIdx.x * 256 + wid * 32;

  // packed static bits for both tiles (coalesced 16B/lane)
  const uint4 e0 = *(const uint4*)(stat2 + ((size_t)(b0 + s15) * 4 + hq) * 16);
  const uint4 e1 = *(const uint4*)(stat2 + ((size_t)(b0 + 16 + s15) * 4 + hq) * 16);

  // msg B-chunks (coalesced 512B/chunk/wave)
  u64 B0[9], B1[9];
  if (!FIRST) {
    const size_t lo0m = (size_t)(b0 + s15) * 32 + (size_t)hq * 8;
#pragma unroll
    for (int i = 0; i < 9; ++i) {
      const int cell = P ? (o * 9 + i) : (i * 9 + o);
      const unsigned char* mp = msg + ((size_t)cell * Bt) * 32;
      B0[i] = *(const u64*)(mp + lo0m);
      B1[i] = *(const u64*)(mp + lo0m + 16 * 32);
    }
  }

  // rebuild static fragments from bitmask (values 0/1; k=45 carries 1.0)
  const u64 sb0 = (u64)e0.x | ((u64)e0.y << 32);
  const u64 sb1 = (u64)e1.x | ((u64)e1.y << 32);
  f16x4 st0[2], st1[2], stc[2];
  {
    const u32 byt0 = (o < 8) ? ((u32)(sb0 >> (o * 8)) & 0xFFu) : (e0.z & 0xFFu);
    const u32 byt1 = (o < 8) ? ((u32)(sb1 >> (o * 8)) & 0xFFu) : (e1.z & 0xFFu);
    const u32 c20 = (e0.z >> 8) & 0xFFu;
    const u32 c21 = (e1.z >> 8) & 0xFFu;
#pragma unroll
    for (int e = 0; e < 4; ++e) {
      st0[0][e] = (_Float16)(float)((byt0 >> e) & 1u);
      st0[1][e] = (_Float16)(float)((byt1 >> e) & 1u);
      st1[0][e] = (_Float16)(float)((byt0 >> (4 + e)) & 1u);
      st1[1][e] = (_Float16)(float)((byt1 >> (4 + e)) & 1u);
      // kidx = 32 + 4*hq + e ; kidx==45 <=> (hq==3 && e==1) -> bias lane 1.0
      const bool bias = (e == 1) && (hq == 3);
      stc[0][e] = bias ? (_Float16)1.f : (_Float16)(float)((c20 >> e) & 1u);
      stc[1][e] = bias ? (_Float16)1.f : (_Float16)(float)((c21 >> e) & 1u);
    }
  }

  asm volatile("s_waitcnt vmcnt(0)" ::: "memory");
  __syncthreads();   // panel ready

  const unsigned char* pl = panel + (size_t)lane * 16;
  const unsigned char* gl = gpanel + (size_t)lane * 16;
  const size_t lo0 = (size_t)(b0 + s15) * 32 + (size_t)hq * 8;
  const size_t lo1 = lo0 + 16 * 32;
#pragma unroll
  for (int jj = 0; jj < 9; ++jj) {
    const int j = (jj == 0) ? 8 : (jj - 1);   // j=8 (global A) first
    f32x4 a0 = 0.f, a1 = 0.f;
#pragma unroll
    for (int s = 0; s < (FIRST ? 2 : 6); ++s) {
      f16x8 af;
      if (j >= PNL_JT) af = *(const f16x8*)(gl + j * 6144 + s * 1024);
      else             af = *(const f16x8*)(pl + j * 6144 + s * 1024);
      const f16x4 alo = __builtin_shufflevector(af, af, 0, 1, 2, 3);
      const int c0 = 2 * s, c1 = 2 * s + 1;
      f16x4 b00, b01;
      if (c0 == 0)      { b00 = st0[0]; b01 = st0[1]; }
      else if (c0 == 2) { b00 = stc[0]; b01 = stc[1]; }
      else              { b00 = as_f16x4(B0[c0 - 3]); b01 = as_f16x4(B1[c0 - 3]); }
      a0 = mfma16(alo, b00, a0);
      a1 = mfma16(alo, b01, a1);
      if (!FIRST || s == 0) {
        const f16x4 ahi = __builtin_shufflevector(af, af, 4, 5, 6, 7);
        f16x4 b10, b11;
        if (c1 == 1) { b10 = st1[0]; b11 = st1[1]; }
        else         { b10 = as_f16x4(B0[c1 - 3]); b11 = as_f16x4(B1[c1 - 3]); }
        a0 = mfma16(ahi, b10, a0);
        a1 = mfma16(ahi, b11, a1);
      }
    }
    f16x4 h0, h1;
#pragma unroll
    for (int r = 0; r < 4; ++r) {
      h0[r] = (_Float16)fmaxf(a0[r], 0.f);
      h1[r] = (_Float16)fmaxf(a1[r], 0.f);
    }
    const int wcell = P ? (o * 9 + j) : (j * 9 + o);
    unsigned char* wp = msg + ((size_t)wcell * Bt) * 32;
    *(u64*)(wp + lo0) = as_u64(h0);
    *(u64*)(wp + lo1) = as_u64(h1);
  }
}

// common layer: grid (Bt/128), 256 thr = 4 waves; wave owns 32 samples;
// acc[2][10] in regs; wdl head fused via shfl reduce (r16-proven).
__global__ __launch_bounds__(256, 3) void common_unf(
    const unsigned char* __restrict__ wsCW, const unsigned char* __restrict__ msg,
    const float* __restrict__ common_b, const float* __restrict__ wdl_w,
    const float* __restrict__ wdl_b, float* __restrict__ out, int Bt)
{
  __shared__ unsigned char sl[CSL_SZ];
  const int tid = threadIdx.x;
  const int lane = tid & 63;
  const int wid = tid >> 6;
  const int s15 = lane & 15, hq = lane >> 4;
  const int b0 = blockIdx.x * 128 + wid * 32;
  const size_t lo0 = (size_t)(b0 + s15) * 32 + (size_t)hq * 8;
  const size_t lo1 = lo0 + 16 * 32;

  f32x4 acc0[10], acc1[10];
#pragma unroll
  for (int mt = 0; mt < 10; ++mt) { acc0[mt] = 0.f; acc1[mt] = 0.f; }

  for (int i = 0; i < 9; ++i) {
    __syncthreads();            // all waves done reading previous slice
    stage_n<256>(wsCW + (size_t)i * CSL_SZ, sl, CSL_SZ, tid);

    u64 m0[9], m1[9];
#pragma unroll
    for (int jj = 0; jj < 9; ++jj) {
      const unsigned char* mp = msg + ((size_t)(i * 9 + jj) * Bt) * 32;
      m0[jj] = *(const u64*)(mp + lo0);
      m1[jj] = *(const u64*)(mp + lo1);
    }
    asm volatile("s_waitcnt vmcnt(0)" ::: "memory");
    __syncthreads();

#pragma unroll
    for (int mt = 0; mt < 10; ++mt) {
      const unsigned char* base = sl + mt * 4608;
#pragma unroll
      for (int p = 0; p < 4; ++p) {
        const f16x8 a8 = *(const f16x8*)(base + p * 1024 + (size_t)lane * 16);
        const f16x4 alo = __builtin_shufflevector(a8, a8, 0, 1, 2, 3);
        const f16x4 ahi = __builtin_shufflevector(a8, a8, 4, 5, 6, 7);
        acc0[mt] = mfma16(alo, as_f16x4(m0[2 * p]),     acc0[mt]);
        acc1[mt] = mfma16(alo, as_f16x4(m1[2 * p]),     acc1[mt]);
        acc0[mt] = mfma16(ahi, as_f16x4(m0[2 * p + 1]), acc0[mt]);
        acc1[mt] = mfma16(ahi, as_f16x4(m1[2 * p + 1]), acc1[mt]);
      }
      const f16x4 al = *(const f16x4*)(base + 4096 + (size_t)lane * 8);
      acc0[mt] = mfma16(al, as_f16x4(m0[8]), acc0[mt]);
      acc1[mt] = mfma16(al, as_f16x4(m1[8]), acc1[mt]);
    }
  }

  float pw0[3] = {0.f, 0.f, 0.f}, pw1[3] = {0.f, 0.f, 0.f};
#pragma unroll
  for (int mt = 0; mt < 10; ++mt) {
#pragma unroll
    for (int r = 0; r < 4; ++r) {
      const int c = mt * 16 + 4 * hq + r;
      if (c < 81) {   // policy (no relu)
        out[(size_t)3 * Bt + (size_t)(b0 + s15) * 81 + c]      = acc0[mt][r] + common_b[c];
        out[(size_t)3 * Bt + (size_t)(b0 + 16 + s15) * 81 + c] = acc1[mt][r] + common_b[c];
      } else if (c < 145) {
        const float h0 = fmaxf(acc0[mt][r] + common_b[c], 0.f);
        const float h1 = fmaxf(acc1[mt][r] + common_b[c], 0.f);
        const int cc = c - 81;
#pragma unroll
        for (int w = 0; w < 3; ++w) {
          const float wv = wdl_w[cc * 3 + w];
          pw0[w] += h0 * wv;
          pw1[w] += h1 * wv;
        }
      }
    }
  }
#pragma unroll
  for (int w = 0; w < 3; ++w) {
    float v0 = pw0[w], v1 = pw1[w];
    v0 += __shfl_xor(v0, 16, 64); v0 += __shfl_xor(v0, 32, 64);
    v1 += __shfl_xor(v1, 16, 64); v1 += __shfl_xor(v1, 32, 64);
    if (hq == 0) {
      const float bb = wdl_b[w];
      out[(size_t)(b0 + s15) * 3 + w]      = v0 + bb;
      out[(size_t)(b0 + 16 + s15) * 3 + w] = v1 + bb;
    }
  }
}

// prologue: pack static features -> 16B/(sample,hq) bitmask entries
// entry.xy = sb (positions 0..7, 8 bits each: chunk0 e0..3, chunk1 e0..3),
// entry.z bits 0..7 = position 8 chunks 0/1, bits 8..11 = chunk2 features.
__global__ __launch_bounds__(256) void conv_static2(
    const float* __restrict__ mask, const float* __restrict__ board,
    unsigned char* __restrict__ stat2, int Bt)
{
  __shared__ float sm[16 * 81];
  __shared__ float sbd[16 * 180];
  const int tid = threadIdx.x;
  const int base_b = blockIdx.x * 16;

  const float4* gm = (const float4*)(mask + (size_t)base_b * 81);
  for (int idx = tid; idx < 324; idx += 256) ((float4*)sm)[idx] = gm[idx];
  const float4* gb = (const float4*)(board + (size_t)base_b * 180);
  for (int idx = tid; idx < 720; idx += 256) ((float4*)sbd)[idx] = gb[idx];
  __syncthreads();

  if (tid >= 64) return;
  const int s15 = tid & 15, hq = tid >> 4;
  const float* lm = sm + s15 * 81;
  const float* lb = sbd + s15 * 180;

#define FEATBIT(o, kidx) \
  (((kidx) < 9  ? lm[(o) * 9 + (kidx)] : \
    (kidx) < 18 ? lb[(o) * 9 + ((kidx) - 9)] : \
    (kidx) < 27 ? lb[90 + (o) * 9 + ((kidx) - 18)] : \
    (kidx) < 36 ? lb[81 + ((kidx) - 27)] : \
    (kidx) < 45 ? lb[90 + 81 + ((kidx) - 36)] : 0.f) > 0.5f ? 1u : 0u)

  u64 sb = 0ull; u32 sx = 0u;
#pragma unroll
  for (int o = 0; o < 9; ++o)
#pragma unroll
    for (int e = 0; e < 4; ++e) {
      const u32 bit0 = FEATBIT(o, 4 * hq + e);
      const u32 bit1 = FEATBIT(o, 16 + 4 * hq + e);
      if (o < 8) sb |= ((u64)bit0 << (o * 8 + e)) | ((u64)bit1 << (o * 8 + 4 + e));
      else       sx |= (bit0 << e) | (bit1 << (4 + e));
    }
#pragma unroll
  for (int e = 0; e < 4; ++e)
    sx |= FEATBIT(0, 32 + 4 * hq + e) << (8 + e);
#undef FEATBIT

  uint4 v;
  v.x = (u32)sb; v.y = (u32)(sb >> 32); v.z = sx; v.w = 0u;
  *(uint4*)(stat2 + ((size_t)(base_b + s15) * 4 + hq) * 16) = v;
}

// prologue: common weights -> i-MAJOR fp16 fragment layout (unfused path)
__global__ __launch_bounds__(256) void conv_common_w2(const float* __restrict__ cw,
                                                      unsigned char* __restrict__ dst) {
  const int gid = blockIdx.x * 256 + threadIdx.x;
  const int NPAIR = 10 * 36 * 64;
  if (gid < NPAIR) {
    const int lane = gid & 63;
    const int t = gid >> 6;
    const int p = t % 4, t2 = t / 4;
    const int i = t2 % 9, mt = t2 / 9;
    const int m = lane & 15, hq = lane >> 4;
    const int c = mt * 16 + m;
    unsigned short v[8];
#pragma unroll
    for (int e = 0; e < 8; ++e) {
      const int ci = i * 9 + 2 * p + (e >> 2);
      const int k = ci * 16 + 4 * hq + (e & 3);
      v[e] = f2h((c < 145) ? cw[(size_t)k * 145 + c] : 0.f);
    }
    const u32 w0 = (u32)v[0] | ((u32)v[1] << 16);
    const u32 w1 = (u32)v[2] | ((u32)v[3] << 16);
    const u32 w2 = (u32)v[4] | ((u32)v[5] << 16);
    const u32 w3 = (u32)v[6] | ((u32)v[7] << 16);
    *(uint4*)(dst + (size_t)i * CSL_SZ + (size_t)mt * 4608
              + (size_t)p * 1024 + (size_t)lane * 16) = make_uint4(w0, w1, w2, w3);
  } else if (gid < NPAIR + 10 * 9 * 64) {
    const int g = gid - NPAIR;
    const int lane = g & 63;
    const int t = g >> 6;
    const int i = t % 9, mt = t / 9;
    const int m = lane & 15, hq = lane >> 4;
    const int c = mt * 16 + m;
    unsigned short v[4];
#pragma unroll
    for (int e = 0; e < 4; ++e) {
      const int k = (i * 9 + 8) * 16 + 4 * hq + e;
      v[e] = f2h((c < 145) ? cw[(size_t)k * 145 + c] : 0.f);
    }
    const u32 w0 = (u32)v[0] | ((u32)v[1] << 16);
    const u32 w1 = (u32)v[2] | ((u32)v[3] << 16);
    *(uint2*)(dst + (size_t)i * CSL_SZ + (size_t)mt * 4608
              + 4096 + (size_t)lane * 8) = make_uint2(w0, w1);
  }
}

// ===========================================================================
// FUSED FALLBACK (r10, proven 734us) + its mt-major common-W prologue
// ===========================================================================

template<int P, int O, int J0, int J1, int OFF>
__device__ __forceinline__ void jt_range(const unsigned char* __restrict__ buf,
    u64 (&msg)[9][9], const u64 (&msgc)[9], f16x4 st0, f16x4 st1, f16x4 stc, int lane)
{
  const unsigned char* abase = buf + (size_t)lane * 16 - OFF;
#pragma unroll
  for (int j = J0; j < J1; ++j) {
    f32x4 acc = 0.f;
#pragma unroll
    for (int sp = 0; sp < 6; ++sp) {
      const f16x8 af = *(const f16x8*)(abase + j * 6144 + sp * 1024);
      const f16x4 alo = __builtin_shufflevector(af, af, 0, 1, 2, 3);
      const f16x4 ahi = __builtin_shufflevector(af, af, 4, 5, 6, 7);
      const int c0 = 2 * sp, c1 = 2 * sp + 1;
      if (c0 == 0)      acc = mfma16(alo, st0, acc);
      else if (c0 == 2) acc = mfma16(alo, stc, acc);
      else              acc = mfma16(alo, as_f16x4(msgc[c0 - 3]), acc);
      if (c1 == 1)      acc = mfma16(ahi, st1, acc);
      else              acc = mfma16(ahi, as_f16x4(msgc[c1 - 3]), acc);
    }
    f16x4 h;
#pragma unroll
    for (int r = 0; r < 4; ++r)
      h[r] = (_Float16)fmaxf(acc[r], 0.f);
    if (P) msg[O][j] = as_u64(h); else msg[j][O] = as_u64(h);
  }
}

template<int P, int O>
__device__ __forceinline__ void do_step_layer(int base, const unsigned char* __restrict__ ws,
    unsigned char* bufA, unsigned char* bufB, u64 (&msg)[9][9],
    u64 sb, u32 sb8, f16x4 stc, int lane, int tid)
{
  const int step = base + P * 9 + O;
  asm volatile("s_waitcnt vmcnt(0)" ::: "memory");
  __syncthreads();
  stage_n<256>(ws + (size_t)step * STEP_BYTES + PHA_SZ, bufB, PHB_SZ, tid);
  f16x4 st0, st1;
  {
    const u32 byt = (O < 8) ? ((u32)(sb >> (O * 8)) & 0xFFu) : sb8;
#pragma unroll
    for (int e = 0; e < 4; ++e) {
      st0[e] = (_Float16)(float)((byt >> e) & 1u);
      st1[e] = (_Float16)(float)((byt >> (4 + e)) & 1u);
    }
  }
  u64 msgc[9];
#pragma unroll
  for (int i = 0; i < 9; ++i)
    msgc[i] = P ? msg[O][i] : msg[i][O];
  jt_range<P, O, 0, 5, 0>(bufA, msg, msgc, st0, st1, stc, lane);
  asm volatile("s_waitcnt vmcnt(0)" ::: "memory");
  __syncthreads();
  if (step + 1 < 54)
    stage_n<256>(ws + (size_t)(step + 1) * STEP_BYTES, bufA, PHA_SZ, tid);
  else
    stage_n<256>(ws + WS_LAYER, bufA, CPA_SZ, tid);
  jt_range<P, O, 5, 9, PHA_SZ>(bufB, msg, msgc, st0, st1, stc, lane);
}

__global__ __launch_bounds__(256, 1) void mix_main(
    const float* __restrict__ mask, const float* __restrict__ board,
    const float* __restrict__ common_b, const float* __restrict__ wdl_w,
    const float* __restrict__ wdl_b, const unsigned char* __restrict__ ws,
    float* __restrict__ out, int Bt)
{
  extern __shared__ unsigned char lds[];
  const int tid = threadIdx.x;
  const int lane = tid & 63;
  const int wid = tid >> 6;
  const int s15 = lane & 15, hq = lane >> 4;
  const int b0 = blockIdx.x * 64 + wid * 16;
  unsigned char* bufA = lds;
  unsigned char* bufB = lds + PHA_SZ;

  stage_n<256>(ws, bufA, PHA_SZ, tid);

  u64 msg[9][9];
#pragma unroll
  for (int a = 0; a < 9; ++a)
#pragma unroll
    for (int b = 0; b < 9; ++b) msg[a][b] = 0ull;

  u64 sb = 0ull;
  u32 sb8 = 0u;
  {
    const int b = b0 + s15;
#pragma unroll
    for (int o = 0; o < 9; ++o)
#pragma unroll
      for (int e = 0; e < 4; ++e) {
        const u32 bit0 = static_feat(mask, board, b, o,      4 * hq + e) > 0.5f;
        const u32 bit1 = static_feat(mask, board, b, o, 16 + 4 * hq + e) > 0.5f;
        if (o < 8) sb |= ((u64)bit0 << (o * 8 + e)) | ((u64)bit1 << (o * 8 + 4 + e));
        else       sb8 |= (bit0 << e) | (bit1 << (4 + e));
      }
  }
  f16x4 stc;
  {
    const int b = b0 + s15;
#pragma unroll
    for (int e = 0; e < 4; ++e) {
      const int kidx = 32 + 4 * hq + e;
      stc[e] = (_Float16)((kidx == 45) ? 1.f : static_feat(mask, board, b, 0, kidx));
    }
  }

#define DO_POS(P, O) do_step_layer<P, O>(base, ws, bufA, bufB, msg, sb, sb8, stc, lane, tid);
  for (int dp = 0; dp < 3; ++dp) {
    const int base = dp * 18;
    DO_POS(0,0) DO_POS(0,1) DO_POS(0,2) DO_POS(0,3) DO_POS(0,4)
    DO_POS(0,5) DO_POS(0,6) DO_POS(0,7) DO_POS(0,8)
    DO_POS(1,0) DO_POS(1,1) DO_POS(1,2) DO_POS(1,3) DO_POS(1,4)
    DO_POS(1,5) DO_POS(1,6) DO_POS(1,7) DO_POS(1,8)
  }
#undef DO_POS

  float pw[3] = {0.f, 0.f, 0.f};
  for (int mt = 0; mt < 10; ++mt) {
    asm volatile("s_waitcnt vmcnt(0)" ::: "memory");
    __syncthreads();
    stage_n<256>(ws + WS_LAYER + (size_t)mt * CMN_STRIDE + CPA_SZ, bufB, CPB_SZ, tid);
    f32x4 a0 = 0.f;
#pragma unroll
    for (int i = 0; i < 5; ++i) {
      const unsigned char* base = bufA + i * 4608;
#pragma unroll
      for (int p = 0; p < 4; ++p) {
        const f16x8 af = *(const f16x8*)(base + p * 1024 + (size_t)lane * 16);
        const f16x4 alo = __builtin_shufflevector(af, af, 0, 1, 2, 3);
        const f16x4 ahi = __builtin_shufflevector(af, af, 4, 5, 6, 7);
        a0 = mfma16(alo, as_f16x4(msg[i][2 * p]),     a0);
        a0 = mfma16(ahi, as_f16x4(msg[i][2 * p + 1]), a0);
      }
      const f16x4 al = *(const f16x4*)(bufA + i * 4608 + 4096 + (size_t)lane * 8);
      a0 = mfma16(al, as_f16x4(msg[i][8]), a0);
    }
    asm volatile("s_waitcnt vmcnt(0)" ::: "memory");
    __syncthreads();
    if (mt + 1 < 10)
      stage_n<256>(ws + WS_LAYER + (size_t)(mt + 1) * CMN_STRIDE, bufA, CPA_SZ, tid);
#pragma unroll
    for (int i = 5; i < 9; ++i) {
      const unsigned char* base = bufB + i * 4608 - CPA_SZ;
#pragma unroll
      for (int p = 0; p < 4; ++p) {
        const f16x8 af = *(const f16x8*)(base + p * 1024 + (size_t)lane * 16);
        const f16x4 alo = __builtin_shufflevector(af, af, 0, 1, 2, 3);
        const f16x4 ahi = __builtin_shufflevector(af, af, 4, 5, 6, 7);
        a0 = mfma16(alo, as_f16x4(msg[i][2 * p]),     a0);
        a0 = mfma16(ahi, as_f16x4(msg[i][2 * p + 1]), a0);
      }
      const f16x4 al = *(const f16x4*)(base + 4096 + (size_t)lane * 8);
      a0 = mfma16(al, as_f16x4(msg[i][8]), a0);
    }
#pragma unroll
    for (int r = 0; r < 4; ++r) {
      const int c = mt * 16 + 4 * hq + r;
      const float bias = (c < 145) ? common_b[c] : 0.f;
      const float v0 = a0[r] + bias;
      if (c < 81) {
        out[(size_t)3 * Bt + (size_t)(b0 + s15) * 81 + c] = v0;
      } else if (c < 145) {
        const float h0 = fmaxf(v0, 0.f);
        const int cc = c - 81;
#pragma unroll
        for (int w = 0; w < 3; ++w)
          pw[w] += h0 * wdl_w[cc * 3 + w];
      }
    }
  }
#pragma unroll
  for (int w = 0; w < 3; ++w) {
    float v0 = pw[w];
    v0 += __shfl_xor(v0, 16, 64); v0 += __shfl_xor(v0, 32, 64);
    if (hq == 0)
      out[(size_t)(b0 + s15) * 3 + w] = v0 + wdl_b[w];
  }
}

// ===========================================================================
// SHARED / FUSED PROLOGUES (r10-proven layouts)
// ===========================================================================

__global__ __launch_bounds__(256) void conv_layer_w(const float* __restrict__ lw,
                                                    const float* __restrict__ lb,
                                                    unsigned char* __restrict__ dst) {
  const int gid = blockIdx.x * 256 + threadIdx.x;
  if (gid >= 54 * 9 * 6 * 64) return;
  const int lane = gid & 63;
  const int t = gid >> 6;
  const int kp = t % 6, t2 = t / 6;
  const int jp = t2 % 9, dop = t2 / 9;
  const int m = lane & 15, hq = lane >> 4;
  unsigned short v[8];
#pragma unroll
  for (int e = 0; e < 8; ++e) {
    const int kc = kp * 2 + (e >> 2);
    const int kidx = kc * 16 + 4 * hq + (e & 3);
    float f = 0.f;
    if (kidx < 45)        f = lw[((size_t)dop * 189 + kidx) * 144 + jp * 16 + m];
    else if (kidx == 45)  f = lb[(size_t)dop * 144 + jp * 16 + m];
    else if (kidx >= 48)  f = lw[((size_t)dop * 189 + (kidx - 3)) * 144 + jp * 16 + m];
    v[e] = f2h(f);
  }
  const u32 w0 = (u32)v[0] | ((u32)v[1] << 16);
  const u32 w1 = (u32)v[2] | ((u32)v[3] << 16);
  const u32 w2 = (u32)v[4] | ((u32)v[5] << 16);
  const u32 w3 = (u32)v[6] | ((u32)v[7] << 16);
  *(uint4*)(dst + (size_t)gid * 16) = make_uint4(w0, w1, w2, w3);
}

__global__ __launch_bounds__(256) void conv_common_w(const float* __restrict__ cw,
                                                     unsigned char* __restrict__ dst) {
  const int gid = blockIdx.x * 256 + threadIdx.x;
  const int NPAIR = 10 * 36 * 64;
  if (gid < NPAIR) {
    const int lane = gid & 63;
    const int t = gid >> 6;
    const int p = t % 4, t2 = t / 4;
    const int i = t2 % 9, mt = t2 / 9;
    const int m = lane & 15, hq = lane >> 4;
    const int c = mt * 16 + m;
    unsigned short v[8];
#pragma unroll
    for (int e = 0; e < 8; ++e) {
      const int ci = i * 9 + 2 * p + (e >> 2);
      const int k = ci * 16 + 4 * hq + (e & 3);
      v[e] = f2h((c < 145) ? cw[(size_t)k * 145 + c] : 0.f);
    }
    const u32 w0 = (u32)v[0] | ((u32)v[1] << 16);
    const u32 w1 = (u32)v[2] | ((u32)v[3] << 16);
    const u32 w2 = (u32)v[4] | ((u32)v[5] << 16);
    const u32 w3 = (u32)v[6] | ((u32)v[7] << 16);
    *(uint4*)(dst + (size_t)WS_LAYER + (size_t)mt * CMN_STRIDE + (size_t)i * 4608
              + (size_t)p * 1024 + (size_t)lane * 16) = make_uint4(w0, w1, w2, w3);
  } else if (gid < NPAIR + 10 * 9 * 64) {
    const int g = gid - NPAIR;
    const int lane = g & 63;
    const int t = g >> 6;
    const int i = t % 9, mt = t / 9;
    const int m = lane & 15, hq = lane >> 4;
    const int c = mt * 16 + m;
    unsigned short v[4];
#pragma unroll
    for (int e = 0; e < 4; ++e) {
      const int k = (i * 9 + 8) * 16 + 4 * hq + e;
      v[e] = f2h((c < 145) ? cw[(size_t)k * 145 + c] : 0.f);
    }
    const u32 w0 = (u32)v[0] | ((u32)v[1] << 16);
    const u32 w1 = (u32)v[2] | ((u32)v[3] << 16);
    *(uint2*)(dst + (size_t)WS_LAYER + (size_t)mt * CMN_STRIDE + (size_t)i * 4608
              + 4096 + (size_t)lane * 8) = make_uint2(w0, w1);
  }
}

// ===========================================================================

extern "C" void kernel_launch(void* const* d_in, const int* in_sizes, int n_in,
                              void* d_out, int out_size, void* d_ws, size_t ws_size,
                              hipStream_t stream) {
  const float* mask     = (const float*)d_in[0];
  const float* board    = (const float*)d_in[1];
  const float* layer_w  = (const float*)d_in[2];
  const float* layer_b  = (const float*)d_in[3];
  const float* common_w = (const float*)d_in[4];
  const float* common_b = (const float*)d_in[5];
  const float* wdl_w    = (const float*)d_in[6];
  const float* wdl_b    = (const float*)d_in[7];
  float* out = (float*)d_out;
  unsigned char* ws = (unsigned char*)d_ws;
  const int Bt = in_sizes[0] / 81;   // 65536

  // ws layout (CW region shared by both paths at WS_LAYER, layouts differ)
  const size_t WS_CW_OFF   = (size_t)WS_LAYER;
  const size_t WS_STAT_OFF = WS_CW_OFF + (size_t)9 * CSL_SZ;
  const size_t WS_MSG_OFF  = WS_STAT_OFF + (size_t)Bt * 64;   // bitmask: 64B/sample
  const size_t WS_NEED     = WS_MSG_OFF + (size_t)81 * Bt * 32;

  hipLaunchKernelGGL(conv_layer_w, dim3((54 * 9 * 6 * 64) / 256), dim3(256), 0, stream,
                     layer_w, layer_b, ws);

  if (ws_size >= WS_NEED) {
    unsigned char* stat2 = ws + WS_STAT_OFF;
    unsigned char* msgp  = ws + WS_MSG_OFF;

    hipLaunchKernelGGL(conv_common_w2, dim3((10 * (36 + 9) * 64 + 255) / 256), dim3(256),
                       0, stream, common_w, ws + WS_CW_OFF);
    hipLaunchKernelGGL(conv_static2, dim3(Bt / 16), dim3(256), 0, stream,
                       mask, board, stat2, Bt);

    const dim3 lgrid(Bt / 256, 9);
    hipLaunchKernelGGL((layer_step<0, 1>), lgrid, dim3(512), 0, stream, ws, stat2, msgp, 0, Bt);
    hipLaunchKernelGGL((layer_step<1, 0>), lgrid, dim3(512), 0, stream, ws, stat2, msgp, 1, Bt);
    hipLaunchKernelGGL((layer_step<0, 0>), lgrid, dim3(512), 0, stream, ws, stat2, msgp, 2, Bt);
    hipLaunchKernelGGL((layer_step<1, 0>), lgrid, dim3(512), 0, stream, ws, stat2, msgp, 3, Bt);
    hipLaunchKernelGGL((layer_step<0, 0>), lgrid, dim3(512), 0, stream, ws, stat2, msgp, 4, Bt);
    hipLaunchKernelGGL((layer_step<1, 0>), lgrid, dim3(512), 0, stream, ws, stat2, msgp, 5, Bt);

    hipLaunchKernelGGL(common_unf, dim3(Bt / 128), dim3(256), 0, stream,
                       ws + WS_CW_OFF, msgp, common_b, wdl_w, wdl_b, out, Bt);
  } else {
    hipLaunchKernelGGL(conv_common_w, dim3((10 * (36 + 9) * 64 + 255) / 256), dim3(256),
                       0, stream, common_w, ws);
    (void)hipFuncSetAttribute((const void*)mix_main,
                              hipFuncAttributeMaxDynamicSharedMemorySize, LDS_TOTAL);
    hipLaunchKernelGGL(mix_main, dim3(Bt / 64), dim3(256), LDS_TOTAL, stream,
                       mask, board, common_b, wdl_w, wdl_b, ws, out, Bt);
  }
}